// Round 20
// baseline (132.448 us; speedup 1.0000x reference)
//
#include <hip/hip_runtime.h>

// ---------------- problem constants ----------------
#define MAX_IN   1024
#define MAX_OUT  4096
#define LOW_RANK 64
#define N_ARCH   16
#define HYP_HID  128
#define BATCH_M  8192   // 4 * 2048

typedef __attribute__((ext_vector_type(8))) short short8;   // 8 x bf16
typedef __attribute__((ext_vector_type(4))) float f32x4;

// round-to-nearest-even fp32 -> bf16
__device__ __forceinline__ unsigned short f2bf(float f) {
  union { float f; unsigned int u; } c; c.f = f;
  unsigned int r = c.u + 0x7fffu + ((c.u >> 16) & 1u);
  return (unsigned short)(r >> 16);
}

__device__ __forceinline__ void gload16(const unsigned short* g, unsigned short* l) {
  __builtin_amdgcn_global_load_lds(
      (const __attribute__((address_space(1))) unsigned int*)(g),
      (__attribute__((address_space(3))) unsigned int*)(l), 16, 0, 0);
}

// non-temporal 16B load (nt-flagged): single-use streams bypass L3 service path
__device__ __forceinline__ f32x4 ntload4(const float* p) {
  return __builtin_nontemporal_load((const f32x4*)p);
}

// ---------------- kernel 1: X fp32 -> bf16 ----------------
// nt-load on x (single-use); Xbf store stays cached (gemm consumes it).
__global__ __launch_bounds__(256) void convert_x(const float* __restrict__ in,
                                                 unsigned short* __restrict__ out) {
  size_t i = (size_t)blockIdx.x * 256 + threadIdx.x;
  f32x4 v = ntload4(in + i * 4);
  ushort4 o;
  o.x = f2bf(v.x); o.y = f2bf(v.y); o.z = f2bf(v.z); o.w = f2bf(v.w);
  *(ushort4*)(out + i * 4) = o;
}

// ---------------- kernel 2: W-build, 4 rows/block, 1024 blocks (R19-verified) ----------------
// nt loads on single-use streams (hyp_w2, base_w) -- the R19 win (-11 us).
// lrf stays cached (reused by all blocks); Wbf store cached (gemm consumes).
__global__ __launch_bounds__(256) void build_w4(
    const float* __restrict__ w1, const float* __restrict__ b1,
    const float* __restrict__ e,
    const float* __restrict__ hyp_w2, const float* __restrict__ hyp_b2,
    const float* __restrict__ base_w, const float* __restrict__ lrf,
    unsigned short* __restrict__ Wbf) {
  __shared__ float hs[HYP_HID];
  __shared__ float lefts[4 * LOW_RANK];
  const int tid = threadIdx.x;
  const int o0 = blockIdx.x * 4;
  const int row0 = blockIdx.x * 256;       // first left-row of this block

  if (tid < HYP_HID) {
    const float4* wr = (const float4*)(w1 + tid * N_ARCH);
    float s = b1[tid];
#pragma unroll
    for (int c = 0; c < 4; c++) {
      float4 wv = wr[c];
      float4 ev = *(const float4*)(e + c * 4);
      s += wv.x * ev.x + wv.y * ev.y + wv.z * ev.z + wv.w * ev.w;
    }
    hs[tid] = fmaxf(s, 0.0f);
  }
  __syncthreads();

  const int lane = tid & 63;
  const int w = tid >> 6;
  const int half = lane >> 5;      // 0: even row of pair, 1: odd row
  const int sub = lane & 31;       // position within row (float4 index)
  const float4 hfv = *(const float4*)(hs + sub * 4);

  // wave w covers left-rows [w*64, w*64+64) as 32 pairs; 1 KB contiguous/instr
  const float* src = hyp_w2 + ((size_t)row0 + w * 64 + half) * HYP_HID + sub * 4;

#define LDJ(j) ntload4(src + (size_t)(j) * 2 * HYP_HID)
#define PROC(v, j)                                                             \
  do {                                                                         \
    float s = v.x * hfv.x + v.y * hfv.y + v.z * hfv.z + v.w * hfv.w;           \
    s += __shfl_xor(s, 16);                                                    \
    s += __shfl_xor(s, 8);                                                     \
    s += __shfl_xor(s, 4);                                                     \
    s += __shfl_xor(s, 2);                                                     \
    s += __shfl_xor(s, 1);                                                     \
    const int rl_ = w * 64 + 2 * (j) + half;                                   \
    if (sub == 0) lefts[rl_] = s + hyp_b2[row0 + rl_];                         \
  } while (0)

  f32x4 v0 = LDJ(0), v1 = LDJ(1), v2 = LDJ(2), v3 = LDJ(3);
#pragma unroll
  for (int jj = 0; jj < 7; jj++) {
    PROC(v0, jj * 4 + 0); v0 = LDJ(jj * 4 + 4);
    PROC(v1, jj * 4 + 1); v1 = LDJ(jj * 4 + 5);
    PROC(v2, jj * 4 + 2); v2 = LDJ(jj * 4 + 6);
    PROC(v3, jj * 4 + 3); v3 = LDJ(jj * 4 + 7);
  }
  PROC(v0, 28); PROC(v1, 29); PROC(v2, 30); PROC(v3, 31);
#undef LDJ
#undef PROC
  __syncthreads();

  // ---- phase 2: thread owns k0=tid*4..+3, all 4 rows ----
  const int k0 = tid * 4;
  f32x4 acc[4];
#pragma unroll
  for (int oi = 0; oi < 4; oi++)
    acc[oi] = ntload4(base_w + (size_t)(o0 + oi) * MAX_IN + k0);   // single-use
#pragma unroll 8
  for (int r = 0; r < LOW_RANK; r++) {
    float4 lv = *(const float4*)(lrf + r * MAX_IN + k0);           // reused -> cached
#pragma unroll
    for (int oi = 0; oi < 4; oi++) {
      const float lw = lefts[oi * LOW_RANK + r];   // LDS broadcast
      acc[oi].x += lw * lv.x; acc[oi].y += lw * lv.y;
      acc[oi].z += lw * lv.z; acc[oi].w += lw * lv.w;
    }
  }
#pragma unroll
  for (int oi = 0; oi < 4; oi++) {
    ushort4 o;
    o.x = f2bf(acc[oi].x); o.y = f2bf(acc[oi].y);
    o.z = f2bf(acc[oi].z); o.w = f2bf(acc[oi].w);
    *(ushort4*)(Wbf + (size_t)(o0 + oi) * MAX_IN + k0) = o;
  }
}

// ---------------- kernel 3: pipelined GEMM + nt C-write ----------------
// 128x256 tile, BK=32, 4 waves (2M x 2N), wave-tile 64x128 (4x8 frags of 16x16x32).
// 3 LDS buffers (72 KB) -> 2 blocks/CU. Prefetch distance 2, counted vmcnt(6).
// XCD macro-map: 16bm x 8bn per XCD, bm-major (B-cycle 4 MB = L2-resident).
// 0-conflict swizzle via pre-swizzled GLOBAL source + linear gload_lds dest.
// NEW: non-temporal C stores (write-once, never re-read) -> no L2/L3
// pollution evicting the staged A/B panels.
__global__ __launch_bounds__(256, 2) void gemm_kernel(
    const unsigned short* __restrict__ A,   // [M][K] bf16
    const unsigned short* __restrict__ B,   // [N][K] bf16 (= W)
    const float* __restrict__ bias,         // [N]
    float* __restrict__ C) {                // [M][N] fp32
  constexpr int K = MAX_IN;
  constexpr int N = MAX_OUT;
  constexpr int ABUF = 128 * 32;           // 4096 ushorts = 8 KB
  constexpr int BBUF = 256 * 32;           // 8192 ushorts = 16 KB
  constexpr int TBUF = ABUF + BBUF;        // 12288 ushorts
  constexpr int NT = K / 32;               // 32 K-tiles
  __shared__ __align__(16) unsigned short lds[3 * TBUF];  // 72 KB

  const int tid = threadIdx.x;
  const int lane = tid & 63;
  const int w = tid >> 6;
  const int wm = w >> 1, wn = w & 1;
  const int fl = lane & 15, hi = lane >> 4;

  const int orig = blockIdx.x;
  const int xcd = orig & 7;
  const int mj = orig >> 3;                     // 0..127
  const int bm = ((xcd >> 1) * 16 + (mj >> 3)) * 128;   // 64 M-tiles
  const int bn = ((xcd & 1) * 8 + (mj & 7)) * 256;      // 16 N-tiles

  // ---- staging coords: slot s holds element (r = s>>2, c = (s&3)^((s>>3)&3)) ----
  const int sA0 = w * 128 + lane;          // + 64*j, j=0..1
  const int rA = sA0 >> 2;
  const int cA = (sA0 & 3) ^ ((sA0 >> 3) & 3);
  const int sB0 = w * 256 + lane;          // + 64*j, j=0..3
  const int rB = sB0 >> 2;
  const int cB = (sB0 & 3) ^ ((sB0 >> 3) & 3);
  const unsigned short* Ag = A + (size_t)(bm + rA) * K + cA * 8;
  const unsigned short* Bg = B + (size_t)(bn + rB) * K + cB * 8;

  // ---- fragment read bases (ushort offsets inside a tile buffer) ----
  const int swz = hi ^ ((fl >> 1) & 3);
  const int abase = (wm * 32 + (fl >> 1)) * 64 + (fl & 1) * 32 + swz * 8;
  const int bbase = (wn * 64 + (fl >> 1)) * 64 + (fl & 1) * 32 + swz * 8;

  f32x4 acc[4][8];
#pragma unroll
  for (int m = 0; m < 4; m++)
#pragma unroll
    for (int n = 0; n < 8; n++) acc[m][n] = (f32x4){0.f, 0.f, 0.f, 0.f};

#define STAGE(p, t)                                                            \
  do {                                                                         \
    unsigned short* la_ = &lds[(p) * TBUF];                                    \
    unsigned short* lb_ = la_ + ABUF;                                          \
    _Pragma("unroll")                                                          \
    for (int j = 0; j < 2; j++)                                                \
      gload16(Ag + (size_t)(16 * j) * K + (t) * 32, &la_[(sA0 + 64 * j) * 8]); \
    _Pragma("unroll")                                                          \
    for (int j = 0; j < 4; j++)                                                \
      gload16(Bg + (size_t)(16 * j) * K + (t) * 32, &lb_[(sB0 + 64 * j) * 8]); \
  } while (0)

  STAGE(0, 0);
  STAGE(1, 1);
  asm volatile("s_waitcnt vmcnt(6)" ::: "memory");
  __builtin_amdgcn_s_barrier();
  __builtin_amdgcn_sched_barrier(0);

  int p = 0;
  for (int t = 0; t < NT; ++t) {
    if (t + 2 < NT) {
      const int pn = (p + 2 >= 3) ? p - 1 : p + 2;
      STAGE(pn, t + 2);
    }
    const unsigned short* la = &lds[p * TBUF];
    const unsigned short* lb = la + ABUF;
    short8 a[4], b[8];
#pragma unroll
    for (int m = 0; m < 4; m++) a[m] = *(const short8*)&la[abase + m * 512];
#pragma unroll
    for (int n = 0; n < 8; n++) b[n] = *(const short8*)&lb[bbase + n * 512];
    __builtin_amdgcn_s_setprio(1);
#pragma unroll
    for (int m = 0; m < 4; m++)
#pragma unroll
      for (int n = 0; n < 8; n++)
        acc[m][n] = __builtin_amdgcn_mfma_f32_16x16x32_bf16(a[m], b[n], acc[m][n], 0, 0, 0);
    __builtin_amdgcn_s_setprio(0);
    if (t + 2 < NT) {
      asm volatile("s_waitcnt vmcnt(6)" ::: "memory");   // tile t+1 landed
    } else if (t + 2 == NT) {
      asm volatile("s_waitcnt vmcnt(0)" ::: "memory");   // final tile landed
    }
    if (t + 1 < NT) {
      __builtin_amdgcn_s_barrier();
      __builtin_amdgcn_sched_barrier(0);
    }
    p = (p + 1 == 3) ? 0 : p + 1;
  }
#undef STAGE

  // ---- epilogue: C/D layout col=lane&15, row=(lane>>4)*4+j; nt stores ----
  float bv[8];
#pragma unroll
  for (int n = 0; n < 8; n++) bv[n] = bias[bn + wn * 128 + n * 16 + fl];
#pragma unroll
  for (int m = 0; m < 4; m++) {
    const int gr0 = bm + wm * 64 + m * 16 + hi * 4;
#pragma unroll
    for (int n = 0; n < 8; n++) {
      const int gc = bn + wn * 128 + n * 16 + fl;
#pragma unroll
      for (int j = 0; j < 4; j++)
        __builtin_nontemporal_store(acc[m][n][j] + bv[n],
                                    &C[(size_t)(gr0 + j) * N + gc]);
    }
  }
}

// ---------------- launcher ----------------
extern "C" void kernel_launch(void* const* d_in, const int* in_sizes, int n_in,
                              void* d_out, int out_size, void* d_ws, size_t ws_size,
                              hipStream_t stream) {
  const float* x      = (const float*)d_in[0];
  const float* embed  = (const float*)d_in[1];
  const float* base_w = (const float*)d_in[2];
  const float* base_b = (const float*)d_in[3];
  const float* lrf    = (const float*)d_in[4];
  const float* w1     = (const float*)d_in[5];
  const float* b1     = (const float*)d_in[6];
  const float* w2     = (const float*)d_in[7];
  const float* b2     = (const float*)d_in[8];
  float* out = (float*)d_out;

  char* ws = (char*)d_ws;
  unsigned short* Xbf = (unsigned short*)ws;                                   // 16 MB
  unsigned short* Wbf = (unsigned short*)(ws + (size_t)BATCH_M * MAX_IN * 2);  // 8 MB

  hipLaunchKernelGGL(convert_x, dim3(BATCH_M * MAX_IN / 1024), dim3(256), 0, stream, x, Xbf);
  hipLaunchKernelGGL(build_w4, dim3(MAX_OUT / 4), dim3(256), 0, stream,
                     w1, b1, embed, w2, b2, base_w, lrf, Wbf);
  hipLaunchKernelGGL(gemm_kernel, dim3((BATCH_M / 128) * (MAX_OUT / 256)), dim3(256), 0, stream,
                     Xbf, Wbf, base_b, out);
}

// Round 21
// 128.157 us; speedup vs baseline: 1.0335x; 1.0335x over previous
//
#include <hip/hip_runtime.h>

// ---------------- problem constants ----------------
#define MAX_IN   1024
#define MAX_OUT  4096
#define LOW_RANK 64
#define N_ARCH   16
#define HYP_HID  128
#define BATCH_M  8192   // 4 * 2048

typedef __attribute__((ext_vector_type(8))) short short8;   // 8 x bf16
typedef __attribute__((ext_vector_type(4))) float f32x4;

// round-to-nearest-even fp32 -> bf16
__device__ __forceinline__ unsigned short f2bf(float f) {
  union { float f; unsigned int u; } c; c.f = f;
  unsigned int r = c.u + 0x7fffu + ((c.u >> 16) & 1u);
  return (unsigned short)(r >> 16);
}

__device__ __forceinline__ void gload16(const unsigned short* g, unsigned short* l) {
  __builtin_amdgcn_global_load_lds(
      (const __attribute__((address_space(1))) unsigned int*)(g),
      (__attribute__((address_space(3))) unsigned int*)(l), 16, 0, 0);
}

// non-temporal 16B load (nt-flagged): single-use streams bypass L3 service path.
// NOTE (R20): nt LOADS help (-11 us, R19); nt scalar STORES hurt (write
// amplification 131->158 MB via partial-line writebacks) -- plain stores only.
__device__ __forceinline__ f32x4 ntload4(const float* p) {
  return __builtin_nontemporal_load((const f32x4*)p);
}

// ---------------- kernel 1: X fp32 -> bf16 ----------------
// nt-load on x (single-use); Xbf store stays cached (gemm consumes it).
__global__ __launch_bounds__(256) void convert_x(const float* __restrict__ in,
                                                 unsigned short* __restrict__ out) {
  size_t i = (size_t)blockIdx.x * 256 + threadIdx.x;
  f32x4 v = ntload4(in + i * 4);
  ushort4 o;
  o.x = f2bf(v.x); o.y = f2bf(v.y); o.z = f2bf(v.z); o.w = f2bf(v.w);
  *(ushort4*)(out + i * 4) = o;
}

// ---------------- kernel 2: W-build, 4 rows/block, 1024 blocks (R19-verified) ----------------
// nt loads on single-use streams (hyp_w2, base_w) -- the R19 win (-11 us).
// lrf stays cached (reused by all blocks); Wbf store cached (gemm consumes).
__global__ __launch_bounds__(256) void build_w4(
    const float* __restrict__ w1, const float* __restrict__ b1,
    const float* __restrict__ e,
    const float* __restrict__ hyp_w2, const float* __restrict__ hyp_b2,
    const float* __restrict__ base_w, const float* __restrict__ lrf,
    unsigned short* __restrict__ Wbf) {
  __shared__ float hs[HYP_HID];
  __shared__ float lefts[4 * LOW_RANK];
  const int tid = threadIdx.x;
  const int o0 = blockIdx.x * 4;
  const int row0 = blockIdx.x * 256;       // first left-row of this block

  if (tid < HYP_HID) {
    const float4* wr = (const float4*)(w1 + tid * N_ARCH);
    float s = b1[tid];
#pragma unroll
    for (int c = 0; c < 4; c++) {
      float4 wv = wr[c];
      float4 ev = *(const float4*)(e + c * 4);
      s += wv.x * ev.x + wv.y * ev.y + wv.z * ev.z + wv.w * ev.w;
    }
    hs[tid] = fmaxf(s, 0.0f);
  }
  __syncthreads();

  const int lane = tid & 63;
  const int w = tid >> 6;
  const int half = lane >> 5;      // 0: even row of pair, 1: odd row
  const int sub = lane & 31;       // position within row (float4 index)
  const float4 hfv = *(const float4*)(hs + sub * 4);

  // wave w covers left-rows [w*64, w*64+64) as 32 pairs; 1 KB contiguous/instr
  const float* src = hyp_w2 + ((size_t)row0 + w * 64 + half) * HYP_HID + sub * 4;

#define LDJ(j) ntload4(src + (size_t)(j) * 2 * HYP_HID)
#define PROC(v, j)                                                             \
  do {                                                                         \
    float s = v.x * hfv.x + v.y * hfv.y + v.z * hfv.z + v.w * hfv.w;           \
    s += __shfl_xor(s, 16);                                                    \
    s += __shfl_xor(s, 8);                                                     \
    s += __shfl_xor(s, 4);                                                     \
    s += __shfl_xor(s, 2);                                                     \
    s += __shfl_xor(s, 1);                                                     \
    const int rl_ = w * 64 + 2 * (j) + half;                                   \
    if (sub == 0) lefts[rl_] = s + hyp_b2[row0 + rl_];                         \
  } while (0)

  f32x4 v0 = LDJ(0), v1 = LDJ(1), v2 = LDJ(2), v3 = LDJ(3);
#pragma unroll
  for (int jj = 0; jj < 7; jj++) {
    PROC(v0, jj * 4 + 0); v0 = LDJ(jj * 4 + 4);
    PROC(v1, jj * 4 + 1); v1 = LDJ(jj * 4 + 5);
    PROC(v2, jj * 4 + 2); v2 = LDJ(jj * 4 + 6);
    PROC(v3, jj * 4 + 3); v3 = LDJ(jj * 4 + 7);
  }
  PROC(v0, 28); PROC(v1, 29); PROC(v2, 30); PROC(v3, 31);
#undef LDJ
#undef PROC
  __syncthreads();

  // ---- phase 2: thread owns k0=tid*4..+3, all 4 rows ----
  const int k0 = tid * 4;
  f32x4 acc[4];
#pragma unroll
  for (int oi = 0; oi < 4; oi++)
    acc[oi] = ntload4(base_w + (size_t)(o0 + oi) * MAX_IN + k0);   // single-use
#pragma unroll 8
  for (int r = 0; r < LOW_RANK; r++) {
    float4 lv = *(const float4*)(lrf + r * MAX_IN + k0);           // reused -> cached
#pragma unroll
    for (int oi = 0; oi < 4; oi++) {
      const float lw = lefts[oi * LOW_RANK + r];   // LDS broadcast
      acc[oi].x += lw * lv.x; acc[oi].y += lw * lv.y;
      acc[oi].z += lw * lv.z; acc[oi].w += lw * lv.w;
    }
  }
#pragma unroll
  for (int oi = 0; oi < 4; oi++) {
    ushort4 o;
    o.x = f2bf(acc[oi].x); o.y = f2bf(acc[oi].y);
    o.z = f2bf(acc[oi].z); o.w = f2bf(acc[oi].w);
    *(ushort4*)(Wbf + (size_t)(o0 + oi) * MAX_IN + k0) = o;
  }
}

// ---------------- kernel 3: pipelined GEMM (R19-verified, ~81 us, 846 TF) ----------------
// 128x256 tile, BK=32, 4 waves (2M x 2N), wave-tile 64x128 (4x8 frags of 16x16x32).
// 3 LDS buffers (72 KB) -> 2 blocks/CU. Prefetch distance 2, counted vmcnt(6).
// XCD macro-map: 16bm x 8bn per XCD, bm-major (B-cycle 4 MB = L2-resident).
// 0-conflict swizzle via pre-swizzled GLOBAL source + linear gload_lds dest.
// PLAIN C stores (nt stores regressed: +20% write amplification, R20).
__global__ __launch_bounds__(256, 2) void gemm_kernel(
    const unsigned short* __restrict__ A,   // [M][K] bf16
    const unsigned short* __restrict__ B,   // [N][K] bf16 (= W)
    const float* __restrict__ bias,         // [N]
    float* __restrict__ C) {                // [M][N] fp32
  constexpr int K = MAX_IN;
  constexpr int N = MAX_OUT;
  constexpr int ABUF = 128 * 32;           // 4096 ushorts = 8 KB
  constexpr int BBUF = 256 * 32;           // 8192 ushorts = 16 KB
  constexpr int TBUF = ABUF + BBUF;        // 12288 ushorts
  constexpr int NT = K / 32;               // 32 K-tiles
  __shared__ __align__(16) unsigned short lds[3 * TBUF];  // 72 KB

  const int tid = threadIdx.x;
  const int lane = tid & 63;
  const int w = tid >> 6;
  const int wm = w >> 1, wn = w & 1;
  const int fl = lane & 15, hi = lane >> 4;

  const int orig = blockIdx.x;
  const int xcd = orig & 7;
  const int mj = orig >> 3;                     // 0..127
  const int bm = ((xcd >> 1) * 16 + (mj >> 3)) * 128;   // 64 M-tiles
  const int bn = ((xcd & 1) * 8 + (mj & 7)) * 256;      // 16 N-tiles

  // ---- staging coords: slot s holds element (r = s>>2, c = (s&3)^((s>>3)&3)) ----
  const int sA0 = w * 128 + lane;          // + 64*j, j=0..1
  const int rA = sA0 >> 2;
  const int cA = (sA0 & 3) ^ ((sA0 >> 3) & 3);
  const int sB0 = w * 256 + lane;          // + 64*j, j=0..3
  const int rB = sB0 >> 2;
  const int cB = (sB0 & 3) ^ ((sB0 >> 3) & 3);
  const unsigned short* Ag = A + (size_t)(bm + rA) * K + cA * 8;
  const unsigned short* Bg = B + (size_t)(bn + rB) * K + cB * 8;

  // ---- fragment read bases (ushort offsets inside a tile buffer) ----
  const int swz = hi ^ ((fl >> 1) & 3);
  const int abase = (wm * 32 + (fl >> 1)) * 64 + (fl & 1) * 32 + swz * 8;
  const int bbase = (wn * 64 + (fl >> 1)) * 64 + (fl & 1) * 32 + swz * 8;

  f32x4 acc[4][8];
#pragma unroll
  for (int m = 0; m < 4; m++)
#pragma unroll
    for (int n = 0; n < 8; n++) acc[m][n] = (f32x4){0.f, 0.f, 0.f, 0.f};

#define STAGE(p, t)                                                            \
  do {                                                                         \
    unsigned short* la_ = &lds[(p) * TBUF];                                    \
    unsigned short* lb_ = la_ + ABUF;                                          \
    _Pragma("unroll")                                                          \
    for (int j = 0; j < 2; j++)                                                \
      gload16(Ag + (size_t)(16 * j) * K + (t) * 32, &la_[(sA0 + 64 * j) * 8]); \
    _Pragma("unroll")                                                          \
    for (int j = 0; j < 4; j++)                                                \
      gload16(Bg + (size_t)(16 * j) * K + (t) * 32, &lb_[(sB0 + 64 * j) * 8]); \
  } while (0)

  STAGE(0, 0);
  STAGE(1, 1);
  asm volatile("s_waitcnt vmcnt(6)" ::: "memory");
  __builtin_amdgcn_s_barrier();
  __builtin_amdgcn_sched_barrier(0);

  int p = 0;
  for (int t = 0; t < NT; ++t) {
    if (t + 2 < NT) {
      const int pn = (p + 2 >= 3) ? p - 1 : p + 2;
      STAGE(pn, t + 2);
    }
    const unsigned short* la = &lds[p * TBUF];
    const unsigned short* lb = la + ABUF;
    short8 a[4], b[8];
#pragma unroll
    for (int m = 0; m < 4; m++) a[m] = *(const short8*)&la[abase + m * 512];
#pragma unroll
    for (int n = 0; n < 8; n++) b[n] = *(const short8*)&lb[bbase + n * 512];
    __builtin_amdgcn_s_setprio(1);
#pragma unroll
    for (int m = 0; m < 4; m++)
#pragma unroll
      for (int n = 0; n < 8; n++)
        acc[m][n] = __builtin_amdgcn_mfma_f32_16x16x32_bf16(a[m], b[n], acc[m][n], 0, 0, 0);
    __builtin_amdgcn_s_setprio(0);
    if (t + 2 < NT) {
      asm volatile("s_waitcnt vmcnt(6)" ::: "memory");   // tile t+1 landed
    } else if (t + 2 == NT) {
      asm volatile("s_waitcnt vmcnt(0)" ::: "memory");   // final tile landed
    }
    if (t + 1 < NT) {
      __builtin_amdgcn_s_barrier();
      __builtin_amdgcn_sched_barrier(0);
    }
    p = (p + 1 == 3) ? 0 : p + 1;
  }
#undef STAGE

  // ---- epilogue: C/D layout col=lane&15, row=(lane>>4)*4+j; plain stores ----
  float bv[8];
#pragma unroll
  for (int n = 0; n < 8; n++) bv[n] = bias[bn + wn * 128 + n * 16 + fl];
#pragma unroll
  for (int m = 0; m < 4; m++) {
    const int gr0 = bm + wm * 64 + m * 16 + hi * 4;
#pragma unroll
    for (int n = 0; n < 8; n++) {
      const int gc = bn + wn * 128 + n * 16 + fl;
#pragma unroll
      for (int j = 0; j < 4; j++)
        C[(size_t)(gr0 + j) * N + gc] = acc[m][n][j] + bv[n];
    }
  }
}

// ---------------- launcher ----------------
extern "C" void kernel_launch(void* const* d_in, const int* in_sizes, int n_in,
                              void* d_out, int out_size, void* d_ws, size_t ws_size,
                              hipStream_t stream) {
  const float* x      = (const float*)d_in[0];
  const float* embed  = (const float*)d_in[1];
  const float* base_w = (const float*)d_in[2];
  const float* base_b = (const float*)d_in[3];
  const float* lrf    = (const float*)d_in[4];
  const float* w1     = (const float*)d_in[5];
  const float* b1     = (const float*)d_in[6];
  const float* w2     = (const float*)d_in[7];
  const float* b2     = (const float*)d_in[8];
  float* out = (float*)d_out;

  char* ws = (char*)d_ws;
  unsigned short* Xbf = (unsigned short*)ws;                                   // 16 MB
  unsigned short* Wbf = (unsigned short*)(ws + (size_t)BATCH_M * MAX_IN * 2);  // 8 MB

  hipLaunchKernelGGL(convert_x, dim3(BATCH_M * MAX_IN / 1024), dim3(256), 0, stream, x, Xbf);
  hipLaunchKernelGGL(build_w4, dim3(MAX_OUT / 4), dim3(256), 0, stream,
                     w1, b1, embed, w2, b2, base_w, lrf, Wbf);
  hipLaunchKernelGGL(gemm_kernel, dim3((BATCH_M / 128) * (MAX_OUT / 256)), dim3(256), 0, stream,
                     Xbf, Wbf, base_b, out);
}